// Round 6
// baseline (653.915 us; speedup 1.0000x reference)
//
#include <hip/hip_runtime.h>
#include <math.h>

#define BB 32
#define CC 3
#define HH 224
#define WW 224
#define HWS (HH*WW)            // 50176
#define NPIX (BB*HWS)          // 1,605,632
#define NTAPS (9*HWS)          // 451,584
#define EPS_IN 1e-5f
#define LNUM 10

// 2D tile: 8 rows x 32 cols, halo RAD=4. One block processes NB=4 batches of
// the SAME tile: tap decode (coords/weights/masks) is batch-invariant, so it
// is hoisted into registers once and reused 4x. RAD=4 covers |offset|<=3
// (P ~ 2e-9 per tap); the cold fixup handles larger, so correctness never
// depends on RAD.
#define TR 8
#define TC 32
#define RAD 4
#define WROWS (TR + 2*RAD)         // 16
#define WCOLS (TC + 2*RAD)         // 40
#define WSTRIDE WCOLS              // LDS index == linear cell id
#define WCELLS (WROWS * WCOLS)     // 640
#define NB 4                       // batches per block
#define NBG (BB/NB)                // 8 batch groups
#define NTILE ((HH/TR) * (WW/TC))  // 28*7 = 196
#define NBLK (NTILE * NBG)         // 1568

__device__ __forceinline__ float fast_tanh(float z) {
    z = fminf(fmaxf(z, -15.f), 15.f);
    float e = __expf(2.f * z);
    return (e - 1.f) * __frcp_rn(e + 1.f);
}

__global__ void zero_kernel(float* __restrict__ p, int n) {
    int i = blockIdx.x * 256 + threadIdx.x;
    if (i < n) p[i] = 0.f;
}

// ------- precompute per-tap: border-masked bilinear weights (float4) and
// corner coords packed as 2 x short (int). Layer-invariant.
__global__ __launch_bounds__(256) void taps_kernel(
    const float* __restrict__ off,   // [18,H,W] batch-0 offset plane
    float4* __restrict__ tw,         // [9,HW] weights (border-masked)
    int*    __restrict__ tc)         // [9,HW] packed (ix0<<16)|(iy0&0xffff)
{
    int gid = blockIdx.x * 256 + threadIdx.x;    // k*HWS + pix, grid exact
    int k = gid / HWS, pix = gid - k * HWS;
    int h = pix / WW, wc = pix - h * WW;
    int ky = k / 3, kx = k - 3 * ky;
    float dy = off[(2 * k)     * HWS + pix];
    float dx = off[(2 * k + 1) * HWS + pix];
    float py = (float)(h  + ky - 1) + dy;
    float px = (float)(wc + kx - 1) + dx;
    float y0f = floorf(py), x0f = floorf(px);
    float fy = py - y0f, fx = px - x0f;
    int iy0 = (int)y0f, ix0 = (int)x0f;
    int iy1 = iy0 + 1,  ix1 = ix0 + 1;
    float vy0 = (iy0 >= 0 && iy0 < HH) ? 1.f : 0.f;
    float vy1 = (iy1 >= 0 && iy1 < HH) ? 1.f : 0.f;
    float vx0 = (ix0 >= 0 && ix0 < WW) ? 1.f : 0.f;
    float vx1 = (ix1 >= 0 && ix1 < WW) ? 1.f : 0.f;
    float4 w;
    w.x = (1.f - fy) * (1.f - fx) * vy0 * vx0;
    w.y = (1.f - fy) * fx         * vy0 * vx1;
    w.z = fy         * (1.f - fx) * vy1 * vx0;
    w.w = fy         * fx         * vy1 * vx1;
    tw[gid] = w;
    int cy = min(max(iy0, -30000), 30000);
    int cx = min(max(ix0, -30000), 30000);
    tc[gid] = (cx << 16) | (cy & 0xffff);
}

__global__ __launch_bounds__(256) void pack_kernel(
    const float* __restrict__ x, float4* __restrict__ xi)
{
    int g = blockIdx.x * 256 + threadIdx.x;
    int b = g / HWS, pix = g - b * HWS;
    const float* xb = x + (size_t)b * (CC * HWS) + pix;
    xi[g] = make_float4(xb[0], xb[HWS], xb[2 * HWS], 0.f);
}

// R6: batch-amortized taps. R5 post-mortem: dominant global stream was the
// tap tables (180 B/pixel/conv ~= 289 MB/dispatch from L3, re-read per
// batch per layer). One block now serves NB=4 batches of one tile: tap
// decode hoisted to registers once (~45 VGPR), hot loop per batch is pure
// {4 ds_read_b128 + 21 FMA} per tap. Staging addresses are batch-invariant
// (precomputed); next batch's staging loads issued before the reduction to
// hide L3 latency. Grid 196 tiles x 8 batch-groups, XCD-chunked swizzle.
template<int DO_NORM>
__global__ __launch_bounds__(256, 3) void conv_fused(
    const float4* __restrict__ xi,       // prev RAW activations [B*HWS]
    const float4* __restrict__ tw,       // [9,HW] masked bilinear weights
    const int*    __restrict__ tc,       // [9,HW] packed corner coords
    const float*  __restrict__ wt,       // [3,3,9]
    const float*  __restrict__ stats_in, // [B*3][2] prev layer
    const float*  __restrict__ gamma,
    const float*  __restrict__ beta,
    float4* __restrict__ yo,             // RAW conv out [B*HWS]
    float* __restrict__ stats_out)       // [B*3][2] this layer
{
    __shared__ float4 win[WROWS * WSTRIDE];
    __shared__ float  w_s[81];
    __shared__ float  red[4][6];

    int t = threadIdx.x;
    if (t < 81) w_s[t] = wt[t];

    int p = blockIdx.x;
    int logical = (p & 7) * (NBLK / 8) + (p >> 3);
    int tile = logical >> 3;             // 0..195
    int bg   = logical & 7;              // batch group
    int b0   = bg * NB;
    int ty = tile / 7, tx = tile - ty * 7;
    int by0 = ty * TR, bx0 = tx * TC;
    int wly = by0 - RAD, wlx = bx0 - RAD;

    int ry = t >> 5, rx = t & 31;
    int pix = (by0 + ry) * WW + (bx0 + rx);

    // ---- batch-invariant staging addresses (3 chunks of 256 cells) ----
    int soff0, soff1, soff2;
    {
        int cell = t;
        int wy = cell / WCOLS, wx = cell - wy * WCOLS;
        soff0 = min(max(wly + wy, 0), HH - 1) * WW + min(max(wlx + wx, 0), WW - 1);
        cell = t + 256;
        wy = cell / WCOLS; wx = cell - wy * WCOLS;
        soff1 = min(max(wly + wy, 0), HH - 1) * WW + min(max(wlx + wx, 0), WW - 1);
        cell = t + 512;
        wy = cell / WCOLS; wx = cell - wy * WCOLS;
        soff2 = min(max(wly + wy, 0), HH - 1) * WW + min(max(wlx + wx, 0), WW - 1);
    }
    bool sval2 = (t + 512 < WCELLS);     // t < 128

    // ---- batch-invariant tap decode -> registers ----
    int    base_[9];
    float4 ww_[9];
    unsigned bad = 0u;
    #pragma unroll
    for (int k = 0; k < 9; ++k) {
        int pc  = tc[k * HWS + pix];
        int iy0 = (int)(short)(pc & 0xffff);
        int ix0 = pc >> 16;
        int cy = iy0 - wly, cx = ix0 - wlx;
        bool inw = ((unsigned)cy <= (unsigned)(WROWS - 2)) &
                   ((unsigned)cx <= (unsigned)(WCOLS - 2));
        float m = inw ? 1.f : 0.f;
        bad |= (inw ? 0u : 1u) << k;
        float4 w = tw[k * HWS + pix];
        w.x *= m; w.y *= m; w.z *= m; w.w *= m;
        ww_[k] = w;
        base_[k] = min(max(cy, 0), WROWS - 2) * WSTRIDE + min(max(cx, 0), WCOLS - 2);
    }

    // ---- prologue: staging loads for batch b0 ----
    const float4* xb = xi + (size_t)b0 * HWS;
    float4 sv0 = xb[soff0];
    float4 sv1 = xb[soff1];
    float4 sv2 = sval2 ? xb[soff2] : make_float4(0.f, 0.f, 0.f, 0.f);

    for (int bi = 0; bi < NB; ++bi) {
        int b = b0 + bi;
        xb = xi + (size_t)b * HWS;

        // uniform per-(b,c) norm params of the PREVIOUS layer
        float mean0=0.f, mean1=0.f, mean2=0.f;
        float g0=1.f, g1=1.f, g2=1.f, bt0=0.f, bt1=0.f, bt2=0.f;
        if (DO_NORM) {
            const float* st = stats_in + b * 6;
            mean0 = st[0] * (1.f/HWS); mean1 = st[2] * (1.f/HWS); mean2 = st[4] * (1.f/HWS);
            float v0 = fmaxf(st[1]*(1.f/HWS) - mean0*mean0, 0.f);
            float v1 = fmaxf(st[3]*(1.f/HWS) - mean1*mean1, 0.f);
            float v2 = fmaxf(st[5]*(1.f/HWS) - mean2*mean2, 0.f);
            g0 = gamma[0] * rsqrtf(v0 + EPS_IN); bt0 = beta[0];
            g1 = gamma[1] * rsqrtf(v1 + EPS_IN); bt1 = beta[1];
            g2 = gamma[2] * rsqrtf(v2 + EPS_IN); bt2 = beta[2];
        }

        // ---- write window (norm+tanh applied on the fly) ----
        {
            float4 v = sv0;
            if (DO_NORM) {
                v.x = fast_tanh((v.x - mean0) * g0 + bt0);
                v.y = fast_tanh((v.y - mean1) * g1 + bt1);
                v.z = fast_tanh((v.z - mean2) * g2 + bt2);
            }
            win[t] = v;
            v = sv1;
            if (DO_NORM) {
                v.x = fast_tanh((v.x - mean0) * g0 + bt0);
                v.y = fast_tanh((v.y - mean1) * g1 + bt1);
                v.z = fast_tanh((v.z - mean2) * g2 + bt2);
            }
            win[t + 256] = v;
            if (sval2) {
                v = sv2;
                if (DO_NORM) {
                    v.x = fast_tanh((v.x - mean0) * g0 + bt0);
                    v.y = fast_tanh((v.y - mean1) * g1 + bt1);
                    v.z = fast_tanh((v.z - mean2) * g2 + bt2);
                }
                win[t + 512] = v;
            }
        }
        __syncthreads();

        // ---- hot tap loop: pure LDS reads + FMA ----
        float acc0 = 0.f, acc1 = 0.f, acc2 = 0.f;
        #pragma unroll
        for (int k = 0; k < 9; ++k) {
            int base = base_[k];
            float4 w = ww_[k];
            float4 v = win[base];
            float s0 = v.x * w.x, s1 = v.y * w.x, s2 = v.z * w.x;
            v = win[base + 1];
            s0 = fmaf(v.x, w.y, s0); s1 = fmaf(v.y, w.y, s1); s2 = fmaf(v.z, w.y, s2);
            v = win[base + WSTRIDE];
            s0 = fmaf(v.x, w.z, s0); s1 = fmaf(v.y, w.z, s1); s2 = fmaf(v.z, w.z, s2);
            v = win[base + WSTRIDE + 1];
            s0 = fmaf(v.x, w.w, s0); s1 = fmaf(v.y, w.w, s1); s2 = fmaf(v.z, w.w, s2);

            acc0 = fmaf(s2, w_s[18 + k], fmaf(s1, w_s[ 9 + k], fmaf(s0, w_s[     k], acc0)));
            acc1 = fmaf(s2, w_s[45 + k], fmaf(s1, w_s[36 + k], fmaf(s0, w_s[27 + k], acc1)));
            acc2 = fmaf(s2, w_s[72 + k], fmaf(s1, w_s[63 + k], fmaf(s0, w_s[54 + k], acc2)));
        }

        // ---- COLD fixup: taps outside the halo, essentially never ----
        if (__builtin_expect(bad != 0u, 0)) {
            unsigned bb = bad;
            while (bb) {
                int k = __ffs(bb) - 1; bb &= bb - 1;
                int pc  = tc[k * HWS + pix];
                int iy0 = (int)(short)(pc & 0xffff);
                int ix0 = pc >> 16;
                float4 w = tw[k * HWS + pix];   // original border-masked weights
                int cy0 = min(max(iy0, 0), HH - 1), cy1 = min(max(iy0 + 1, 0), HH - 1);
                int cx0 = min(max(ix0, 0), WW - 1), cx1 = min(max(ix0 + 1, 0), WW - 1);
                float s0, s1, s2;
                float4 v = xb[cy0 * WW + cx0];
                if (DO_NORM) { v.x = fast_tanh((v.x-mean0)*g0+bt0); v.y = fast_tanh((v.y-mean1)*g1+bt1); v.z = fast_tanh((v.z-mean2)*g2+bt2); }
                s0 = v.x * w.x; s1 = v.y * w.x; s2 = v.z * w.x;
                v = xb[cy0 * WW + cx1];
                if (DO_NORM) { v.x = fast_tanh((v.x-mean0)*g0+bt0); v.y = fast_tanh((v.y-mean1)*g1+bt1); v.z = fast_tanh((v.z-mean2)*g2+bt2); }
                s0 = fmaf(v.x, w.y, s0); s1 = fmaf(v.y, w.y, s1); s2 = fmaf(v.z, w.y, s2);
                v = xb[cy1 * WW + cx0];
                if (DO_NORM) { v.x = fast_tanh((v.x-mean0)*g0+bt0); v.y = fast_tanh((v.y-mean1)*g1+bt1); v.z = fast_tanh((v.z-mean2)*g2+bt2); }
                s0 = fmaf(v.x, w.z, s0); s1 = fmaf(v.y, w.z, s1); s2 = fmaf(v.z, w.z, s2);
                v = xb[cy1 * WW + cx1];
                if (DO_NORM) { v.x = fast_tanh((v.x-mean0)*g0+bt0); v.y = fast_tanh((v.y-mean1)*g1+bt1); v.z = fast_tanh((v.z-mean2)*g2+bt2); }
                s0 = fmaf(v.x, w.w, s0); s1 = fmaf(v.y, w.w, s1); s2 = fmaf(v.z, w.w, s2);
                acc0 = fmaf(s2, w_s[18 + k], fmaf(s1, w_s[ 9 + k], fmaf(s0, w_s[     k], acc0)));
                acc1 = fmaf(s2, w_s[45 + k], fmaf(s1, w_s[36 + k], fmaf(s0, w_s[27 + k], acc1)));
                acc2 = fmaf(s2, w_s[72 + k], fmaf(s1, w_s[63 + k], fmaf(s0, w_s[54 + k], acc2)));
            }
        }

        yo[(size_t)b * HWS + pix] = make_float4(acc0, acc1, acc2, 0.f);

        // ---- preload next batch's staging (hides L3 latency under reduction) ----
        float4 nv0 = sv0, nv1 = sv1, nv2 = sv2;
        if (bi + 1 < NB) {
            const float4* xbn = xi + (size_t)(b + 1) * HWS;
            nv0 = xbn[soff0];
            nv1 = xbn[soff1];
            nv2 = sval2 ? xbn[soff2] : nv2;
        }

        // ---- per-(b,channel) sum / sumsq reduction ----
        float s0r = acc0, q0 = acc0 * acc0;
        float s1r = acc1, q1 = acc1 * acc1;
        float s2r = acc2, q2 = acc2 * acc2;
        #pragma unroll
        for (int o = 32; o > 0; o >>= 1) {
            s0r += __shfl_down(s0r, o); q0 += __shfl_down(q0, o);
            s1r += __shfl_down(s1r, o); q1 += __shfl_down(q1, o);
            s2r += __shfl_down(s2r, o); q2 += __shfl_down(q2, o);
        }
        int wave = t >> 6, lane = t & 63;
        if (lane == 0) {
            red[wave][0] = s0r; red[wave][1] = q0;
            red[wave][2] = s1r; red[wave][3] = q1;
            red[wave][4] = s2r; red[wave][5] = q2;
        }
        __syncthreads();
        if (t < 6) {
            float v = red[0][t] + red[1][t] + red[2][t] + red[3][t];
            int ch = t >> 1, which = t & 1;
            atomicAdd(&stats_out[(b * 3 + ch) * 2 + which], v);
        }
        __syncthreads();   // protect win (next stage overwrite) and red

        sv0 = nv0; sv1 = nv1; sv2 = nv2;
    }
}

__global__ __launch_bounds__(256) void norm_final(
    const float4* __restrict__ y, float* __restrict__ outp,
    const float* __restrict__ stats,
    const float* __restrict__ gamma, const float* __restrict__ beta)
{
    int q = blockIdx.x;
    int logical = (q & 7) * ((NPIX/256) / 8) + (q >> 3);
    int b     = logical & 31;
    int chunk = logical >> 5;
    int pix   = chunk * 256 + threadIdx.x;

    float4 v = y[b * HWS + pix];
    float vin[3] = {v.x, v.y, v.z};
    float r[3];
    #pragma unroll
    for (int c = 0; c < 3; ++c) {
        float s  = stats[(b * 3 + c) * 2 + 0];
        float qq = stats[(b * 3 + c) * 2 + 1];
        float mean = s * (1.f / HWS);
        float var  = fmaxf(qq * (1.f / HWS) - mean * mean, 0.f);
        float gsc  = gamma[c] * rsqrtf(var + EPS_IN);
        r[c] = fast_tanh((vin[c] - mean) * gsc + beta[c]);
    }
    float* ob = outp + (size_t)b * (CC * HWS) + pix;
    ob[0]       = r[0];
    ob[HWS]     = r[1];
    ob[2 * HWS] = r[2];
}

extern "C" void kernel_launch(void* const* d_in, const int* in_sizes, int n_in,
                              void* d_out, int out_size, void* d_ws, size_t ws_size,
                              hipStream_t stream) {
    const float* x     = (const float*)d_in[0];
    const float* wt    = (const float*)d_in[1];
    const float* off   = (const float*)d_in[2];
    const float* gamma = (const float*)d_in[3];
    const float* beta  = (const float*)d_in[4];

    float* out  = (float*)d_out;
    float*  bufA = (float*)d_ws;                             // 25.7 MB
    float*  bufB = bufA + (size_t)NPIX * 4;                  // 25.7 MB
    float4* tw   = (float4*)(bufB + (size_t)NPIX * 4);       // 7.2 MB
    int*    tc   = (int*)((char*)tw + (size_t)NTAPS * 16);   // 1.8 MB
    float*  stats = (float*)((char*)tc + (size_t)NTAPS * 4); // 7.7 KB
    // ws total ~= 60.5 MB

    zero_kernel<<<(LNUM * 192 + 255) / 256, 256, 0, stream>>>(stats, LNUM * 192);
    taps_kernel<<<NTAPS / 256, 256, 0, stream>>>(off, tw, tc);
    pack_kernel<<<NPIX / 256, 256, 0, stream>>>(x, (float4*)bufB);

    const float4* cur = (const float4*)bufB;
    const float* st_prev = nullptr;
    for (int it = 0; it < LNUM; ++it) {
        float4* dst = (float4*)((it & 1) ? bufB : bufA);
        float* st = stats + it * 192;
        if (it == 0)
            conv_fused<0><<<NBLK, 256, 0, stream>>>(cur, tw, tc, wt, nullptr,
                                                    gamma, beta, dst, st);
        else
            conv_fused<1><<<NBLK, 256, 0, stream>>>(cur, tw, tc, wt, st_prev,
                                                    gamma, beta, dst, st);
        cur = dst;
        st_prev = st;
    }
    norm_final<<<NPIX / 256, 256, 0, stream>>>(cur, out, st_prev, gamma, beta);
}